// Round 11
// baseline (147.343 us; speedup 1.0000x reference)
//
#include <hip/hip_runtime.h>
#include <cstdint>

// CapsuleLayer dynamic routing: B=256, R=1152, C=10, O=16, I=8, 3 iters.
// fp32 in, fp32 out. Block = (c, 2 batches), 512 threads (8 waves -> 4
// waves/SIMD at 2 blocks/CU, up from round 10's 384/2.25). u for both
// batches in dynamic LDS (76 KB) as packed bf16 pairs, p-stride 1189
// (% 32 == 5 -> 2-way read conflicts, free). Phase 1 is software-pipelined
// (distance 1): next iteration's 8 float4 loads issue before current
// compute -> latency hidden by compute + LDS writes. Pass 0 fused into
// phase 1. No persistent per-thread u (rounds 8/9: spill). b_ij never
// stored: with b0=0, logit_k = u . (v0 + ... + v_{k-1}).
#define BB 256
#define RR 1152
#define CC 10
#define OO 16
#define II 8
#define NT 512
#define GG 2
#define NWAVE (NT / 64)
#define NIT (RR / 64)      // 18 phase-1 iterations (64 r-rows each)
#define PSTR 1189          // p-row stride in words; 1189 % 32 == 5

__device__ __forceinline__ uint32_t f2bf(float f) {
    union { float f; uint32_t i; } v; v.f = f;
    return (v.i + 0x7fffu + ((v.i >> 16) & 1u)) >> 16;   // RNE
}
__device__ __forceinline__ void unpack2(uint32_t pk, float& lo, float& hi) {
    union { uint32_t i; float f; } a, b;
    a.i = pk << 16; b.i = pk & 0xffff0000u;
    lo = a.f; hi = b.f;
}
__device__ __forceinline__ float dot8(float4 a, float4 b, float4 xa, float4 xb) {
    float s = 0.f;
    s = fmaf(a.x, xa.x, s); s = fmaf(a.y, xa.y, s);
    s = fmaf(a.z, xa.z, s); s = fmaf(a.w, xa.w, s);
    s = fmaf(b.x, xb.x, s); s = fmaf(b.y, xb.y, s);
    s = fmaf(b.z, xb.z, s); s = fmaf(b.w, xb.w, s);
    return s;
}

__global__ __launch_bounds__(NT)
void k_caps(const float* __restrict__ x, const float* __restrict__ W,
            float* __restrict__ out) {
    extern __shared__ uint32_t u2[];          // [GG][8][PSTR] packed bf16 pairs
    __shared__ float part[NWAVE][GG][17];
    __shared__ float p0s[NWAVE][8][GG][2];    // [wv][p][g][half]
    __shared__ float wsum[GG][OO];

    const int t = threadIdx.x;
    const int c  = blockIdx.x / (BB / GG);    // c-major: 128 blocks share W-slice
    const int b0 = (blockIdx.x % (BB / GG)) * GG;
    const int wv = t >> 6, l = t & 63;
    const int rg = t >> 3, p = t & 7;         // phase 1: 64 r-rows x 8 o-pairs

    uint32_t* uA = u2;                        // batch b0
    uint32_t* uB = u2 + 8 * PSTR;             // batch b0+1

    // ---- Phase 1 (pipelined): u[r,2p:2p+2] both batches -> LDS; pass-0 sums ----
    float s00 = 0.f, s01 = 0.f, s10 = 0.f, s11 = 0.f;

    const float* wp0 = W + (((size_t)rg * CC + c) * OO + 2 * p) * II;
    const float* xq0 = x + ((size_t)b0 * RR + rg) * II;
    float4 a0 = *reinterpret_cast<const float4*>(wp0);
    float4 a1 = *reinterpret_cast<const float4*>(wp0 + 4);
    float4 c0 = *reinterpret_cast<const float4*>(wp0 + 8);
    float4 c1 = *reinterpret_cast<const float4*>(wp0 + 12);
    float4 x00 = *reinterpret_cast<const float4*>(xq0);
    float4 x01 = *reinterpret_cast<const float4*>(xq0 + 4);
    float4 x10 = *reinterpret_cast<const float4*>(xq0 + (size_t)RR * II);
    float4 x11 = *reinterpret_cast<const float4*>(xq0 + (size_t)RR * II + 4);

    for (int it = 0; it < NIT; ++it) {
        const int r = it * 64 + rg;
        float4 na0, na1, nc0, nc1, nx00, nx01, nx10, nx11;
        if (it + 1 < NIT) {                   // prefetch next iteration
            const int rn = r + 64;
            const float* wp = W + (((size_t)rn * CC + c) * OO + 2 * p) * II;
            const float* xq = x + ((size_t)b0 * RR + rn) * II;
            na0 = *reinterpret_cast<const float4*>(wp);
            na1 = *reinterpret_cast<const float4*>(wp + 4);
            nc0 = *reinterpret_cast<const float4*>(wp + 8);
            nc1 = *reinterpret_cast<const float4*>(wp + 12);
            nx00 = *reinterpret_cast<const float4*>(xq);
            nx01 = *reinterpret_cast<const float4*>(xq + 4);
            nx10 = *reinterpret_cast<const float4*>(xq + (size_t)RR * II);
            nx11 = *reinterpret_cast<const float4*>(xq + (size_t)RR * II + 4);
        }
        float lo0 = dot8(a0, a1, x00, x01);   // o=2p,   g=0
        float hi0 = dot8(c0, c1, x00, x01);   // o=2p+1, g=0
        float lo1 = dot8(a0, a1, x10, x11);   // o=2p,   g=1
        float hi1 = dot8(c0, c1, x10, x11);   // o=2p+1, g=1
        s00 += lo0; s01 += hi0; s10 += lo1; s11 += hi1;
        uA[p * PSTR + r] = f2bf(lo0) | (f2bf(hi0) << 16);
        uB[p * PSTR + r] = f2bf(lo1) | (f2bf(hi1) << 16);
        a0 = na0; a1 = na1; c0 = nc0; c1 = nc1;
        x00 = nx00; x01 = nx01; x10 = nx10; x11 = nx11;
    }
    // reduce pass-0 partials over the 8 r-lanes sharing p (masks 8,16,32)
#pragma unroll
    for (int m = 8; m < 64; m <<= 1) {
        s00 += __shfl_xor(s00, m); s01 += __shfl_xor(s01, m);
        s10 += __shfl_xor(s10, m); s11 += __shfl_xor(s11, m);
    }
    if (l < 8) {
        p0s[wv][l][0][0] = s00; p0s[wv][l][0][1] = s01;
        p0s[wv][l][1][0] = s10; p0s[wv][l][1][1] = s11;
    }
    __syncthreads();

    if (t < GG * OO) {   // g = t>>4, o = t&15 (wave 0)
        const int g = t >> 4, o = t & 15;
        float s = 0.f;
#pragma unroll
        for (int w = 0; w < NWAVE; ++w) s += p0s[w][o >> 1][g][o & 1];
        s *= (1.0f / RR);                     // softmax(0) = 1/R
        float ss = s * s;                     // squash over 16-lane o-group
        ss += __shfl_xor(ss, 1); ss += __shfl_xor(ss, 2);
        ss += __shfl_xor(ss, 4); ss += __shfl_xor(ss, 8);
        wsum[g][o] = s * (ss / ((1.0f + ss) * sqrtf(ss + 1e-7f)));  // v0
    }
    __syncthreads();

    // ---- Phase 2: passes 1 and 2 from LDS ----
    for (int pass = 1; pass < 3; ++pass) {
#pragma unroll
        for (int g = 0; g < GG; ++g) {
            const uint32_t* ug = g ? uB : uA;
            float wreg[OO];
#pragma unroll
            for (int k = 0; k < OO; ++k) wreg[k] = wsum[g][k];  // broadcast
            float num[OO];
#pragma unroll
            for (int k = 0; k < OO; ++k) num[k] = 0.f;
            float den = 0.f;

#pragma unroll
            for (int k = 0; k < 3; ++k) {
                const int r = t + NT * k;
                if (r < RR) {                 // wave-uniform guard
                    float ur[OO];
#pragma unroll
                    for (int pp = 0; pp < 8; ++pp)  // bank=(5pp+r)%32: 2-way, free
                        unpack2(ug[pp * PSTR + r], ur[2 * pp], ur[2 * pp + 1]);
                    float lg = 0.f;
#pragma unroll
                    for (int k2 = 0; k2 < OO; ++k2) lg = fmaf(ur[k2], wreg[k2], lg);
                    float e = __expf(lg);     // |logit| <~ 40: fp32-safe
                    den += e;
#pragma unroll
                    for (int k2 = 0; k2 < OO; ++k2) num[k2] = fmaf(e, ur[k2], num[k2]);
                }
            }

#pragma unroll
            for (int m = 1; m < 64; m <<= 1) {
#pragma unroll
                for (int k = 0; k < OO; ++k) num[k] += __shfl_xor(num[k], m);
                den += __shfl_xor(den, m);
            }
            if (l == 0) {
#pragma unroll
                for (int k = 0; k < OO; ++k) part[wv][g][k] = num[k];
                part[wv][g][16] = den;
            }
        }
        __syncthreads();

        if (t < GG * OO) {
            const int g = t >> 4, o = t & 15;
            float nf = 0.f, df = 0.f;
#pragma unroll
            for (int w = 0; w < NWAVE; ++w) {
                nf += part[w][g][o];
                df += part[w][g][16];
            }
            float s = nf / df;
            float ss = s * s;
            ss += __shfl_xor(ss, 1); ss += __shfl_xor(ss, 2);
            ss += __shfl_xor(ss, 4); ss += __shfl_xor(ss, 8);
            float v = s * (ss / ((1.0f + ss) * sqrtf(ss + 1e-7f)));
            if (pass == 2)
                out[((size_t)(b0 + g) * CC + c) * OO + o] = v;
            else
                wsum[g][o] += v;
        }
        __syncthreads();
    }
}

extern "C" void kernel_launch(void* const* d_in, const int* in_sizes, int n_in,
                              void* d_out, int out_size, void* d_ws, size_t ws_size,
                              hipStream_t stream) {
    const float* x = (const float*)d_in[0];  // (B,R,I) fp32
    const float* W = (const float*)d_in[1];  // (R,C,O,I) fp32
    if (n_in >= 2 && in_sizes[0] == RR * CC * OO * II &&
        in_sizes[1] == BB * RR * II) {
        const float* tmp = x; x = W; W = tmp;
    }
    float* out = (float*)d_out;              // (B,1,C,O,1) fp32

    const size_t dyn_lds = (size_t)GG * 8 * PSTR * 4;   // 76,096 B
    k_caps<<<CC * (BB / GG), NT, dyn_lds, stream>>>(x, W, out);
}